// Round 1
// baseline (454.950 us; speedup 1.0000x reference)
//
#include <hip/hip_runtime.h>

#define B_   128
#define L_   336
#define N_   321
#define E_   128
#define LAT_ 64

typedef float f4 __attribute__((ext_vector_type(4)));

// out layout (flat concat, fp32):
//   h     : [B][N][E]    offset 0
//   h_hat : [B][N][E]    offset B*N*E
//   mu    : [B][N][LAT]  offset 2*B*N*E
//   var   : [B][N][LAT]  offset 2*B*N*E + B*N*LAT
#define OUT_HH  (B_*N_*E_)
#define OUT_MU  (2*B_*N_*E_)
#define OUT_VAR (2*B_*N_*E_ + B_*N_*LAT_)

// ---------------------------------------------------------------------------
// Kernel 1: transpose x[B][L][N] -> xp[N][B][L]   (coalesced both sides)
// ---------------------------------------------------------------------------
__global__ __launch_bounds__(256) void k_transpose(const float* __restrict__ x,
                                                   float* __restrict__ xp) {
    __shared__ float t[32][33];
    const int n0 = blockIdx.x * 32;
    const int l0 = blockIdx.y * 32;
    const int b  = blockIdx.z;
    const int tx = threadIdx.x;   // 0..31
    const int ty = threadIdx.y;   // 0..7

    const float* xb = x + (size_t)b * L_ * N_;
#pragma unroll
    for (int k = 0; k < 4; ++k) {
        const int l = l0 + ty + 8 * k;
        const int n = n0 + tx;
        if (l < L_ && n < N_) t[ty + 8 * k][tx] = xb[l * N_ + n];
    }
    __syncthreads();
    float* xpb = xp + (size_t)b * L_;
#pragma unroll
    for (int k = 0; k < 4; ++k) {
        const int n = n0 + ty + 8 * k;
        const int l = l0 + tx;
        if (l < L_ && n < N_) xpb[(size_t)n * (B_ * L_) + l] = t[tx][ty + 8 * k];
    }
}

// ---------------------------------------------------------------------------
// Kernel 2: fused grouped GEMM. One 64-thread block per (channel n, b-tile).
//   stage 1: h[32 x 128] = xp[n, b0:b0+32, :336] @ W_embed[n]  (+ b_embed)
//   epilogue: h_hat = sigmoid(time_x) * h ; both written out; h_hat -> LDS^T
//   stage 2: [mu | var][32 x 128] = h_hat @ [W_mu[n] | W_var[n]] (+ biases)
// Per thread: 8 rows x 8 cols fp32 register tile.
// ---------------------------------------------------------------------------
#define BT 32
#define KT 16
#define AS 36   // padded LDS stride for transposed A / h_hat tiles

template <bool XP>
__global__ __launch_bounds__(64) void k_fused(const float* __restrict__ xsrc,
                                              const float* __restrict__ time_x,
                                              const float* __restrict__ W_embed,
                                              const float* __restrict__ b_embed,
                                              const float* __restrict__ W_mu,
                                              const float* __restrict__ b_mu,
                                              const float* __restrict__ W_var,
                                              const float* __restrict__ b_var,
                                              float* __restrict__ out) {
    __shared__ float A2[128][AS];     // stage-2 A (h_hat^T); rows 0..15 alias stage-1 A-tile
    __shared__ float Wt[KT][128];     // W tile (stage 1) / [W_mu|W_var] tile (stage 2)

    const int tid = threadIdx.x;      // 0..63
    const int tx  = tid & 15;         // col group
    const int ty  = tid >> 4;         // row group (0..3)
    const int n   = blockIdx.x >> 2;
    const int b0  = (blockIdx.x & 3) * BT;

    float acc[8][8];
#pragma unroll
    for (int i = 0; i < 8; ++i)
#pragma unroll
        for (int j = 0; j < 8; ++j) acc[i][j] = 0.f;

    float (*At)[AS] = (float (*)[AS])A2;   // [KT][AS] alias

    // ---------------- stage 1: K = 336 in 21 chunks of 16 ----------------
    for (int k0 = 0; k0 < L_; k0 += KT) {
        // stage A-tile (transposed into LDS): 32 rows x 16 k
#pragma unroll
        for (int h = 0; h < 2; ++h) {
            const int r  = (tid >> 2) + h * 16;
            const int qk = tid & 3;
            f4 v;
            if (XP) {
                v = *(const f4*)(xsrc + (size_t)n * (B_ * L_) + (b0 + r) * L_ + k0 + qk * 4);
            } else {
#pragma unroll
                for (int j = 0; j < 4; ++j)
                    v[j] = xsrc[(size_t)(b0 + r) * (L_ * N_) + (k0 + qk * 4 + j) * N_ + n];
            }
#pragma unroll
            for (int j = 0; j < 4; ++j) At[qk * 4 + j][r] = v[j];
        }
        // stage W-tile: 16 x 128
#pragma unroll
        for (int i = 0; i < 8; ++i) {
            const int f  = tid + 64 * i;
            const int kk = f >> 5;
            const int c4 = f & 31;
            f4 v = *(const f4*)(W_embed + (size_t)n * (L_ * E_) + (k0 + kk) * E_ + c4 * 4);
            *(f4*)&Wt[kk][c4 * 4] = v;
        }
        __syncthreads();
#pragma unroll
        for (int kk = 0; kk < KT; ++kk) {
            f4 a0 = *(const f4*)&At[kk][ty * 8];
            f4 a1 = *(const f4*)&At[kk][ty * 8 + 4];
            f4 w0 = *(const f4*)&Wt[kk][tx * 4];
            f4 w1 = *(const f4*)&Wt[kk][64 + tx * 4];
#pragma unroll
            for (int i = 0; i < 4; ++i)
#pragma unroll
                for (int j = 0; j < 4; ++j) {
                    acc[i][j]         += a0[i] * w0[j];
                    acc[i][j + 4]     += a0[i] * w1[j];
                    acc[i + 4][j]     += a1[i] * w0[j];
                    acc[i + 4][j + 4] += a1[i] * w1[j];
                }
        }
        __syncthreads();
    }

    // ---------------- epilogue 1: bias, write h, h_hat; h_hat^T -> LDS ----
    const int c_lo = tx * 4, c_hi = 64 + tx * 4;
    f4 be0 = *(const f4*)(b_embed + n * E_ + c_lo);
    f4 be1 = *(const f4*)(b_embed + n * E_ + c_hi);
#pragma unroll
    for (int i = 0; i < 8; ++i) {
        const int row  = b0 + ty * 8 + i;
        const int base = (row * N_ + n) * E_;
        f4 h0, h1;
#pragma unroll
        for (int j = 0; j < 4; ++j) { h0[j] = acc[i][j] + be0[j]; h1[j] = acc[i][j + 4] + be1[j]; }
        *(f4*)(out + base + c_lo) = h0;
        *(f4*)(out + base + c_hi) = h1;
        f4 t0 = *(const f4*)(time_x + base + c_lo);
        f4 t1 = *(const f4*)(time_x + base + c_hi);
        f4 hh0, hh1;
#pragma unroll
        for (int j = 0; j < 4; ++j) {
            hh0[j] = h0[j] * (1.f / (1.f + expf(-t0[j])));
            hh1[j] = h1[j] * (1.f / (1.f + expf(-t1[j])));
        }
        *(f4*)(out + OUT_HH + base + c_lo) = hh0;
        *(f4*)(out + OUT_HH + base + c_hi) = hh1;
        const int r = ty * 8 + i;
#pragma unroll
        for (int j = 0; j < 4; ++j) { A2[c_lo + j][r] = hh0[j]; A2[c_hi + j][r] = hh1[j]; }
    }
    __syncthreads();

    // ---------------- stage 2: [mu|var] = h_hat @ [W_mu|W_var], K = 128 ---
#pragma unroll
    for (int i = 0; i < 8; ++i)
#pragma unroll
        for (int j = 0; j < 8; ++j) acc[i][j] = 0.f;

    for (int k2 = 0; k2 < 8; ++k2) {
#pragma unroll
        for (int i = 0; i < 8; ++i) {
            const int f  = tid + 64 * i;
            const int kk = f >> 5;
            const int c4 = f & 31;
            const int e  = k2 * KT + kk;
            f4 v;
            if (c4 < 16) v = *(const f4*)(W_mu  + (size_t)n * (E_ * LAT_) + e * LAT_ + c4 * 4);
            else         v = *(const f4*)(W_var + (size_t)n * (E_ * LAT_) + e * LAT_ + (c4 - 16) * 4);
            *(f4*)&Wt[kk][c4 * 4] = v;
        }
        __syncthreads();
#pragma unroll
        for (int kk = 0; kk < KT; ++kk) {
            f4 a0 = *(const f4*)&A2[k2 * KT + kk][ty * 8];
            f4 a1 = *(const f4*)&A2[k2 * KT + kk][ty * 8 + 4];
            f4 w0 = *(const f4*)&Wt[kk][tx * 4];
            f4 w1 = *(const f4*)&Wt[kk][64 + tx * 4];
#pragma unroll
            for (int i = 0; i < 4; ++i)
#pragma unroll
                for (int j = 0; j < 4; ++j) {
                    acc[i][j]         += a0[i] * w0[j];
                    acc[i][j + 4]     += a0[i] * w1[j];
                    acc[i + 4][j]     += a1[i] * w0[j];
                    acc[i + 4][j + 4] += a1[i] * w1[j];
                }
        }
        __syncthreads();
    }

    // ---------------- epilogue 2: biases + store mu / var ------------------
    f4 bm = *(const f4*)(b_mu  + n * LAT_ + tx * 4);
    f4 bv = *(const f4*)(b_var + n * LAT_ + tx * 4);
#pragma unroll
    for (int i = 0; i < 8; ++i) {
        const int row  = b0 + ty * 8 + i;
        const int base = (row * N_ + n) * LAT_;
        f4 m, v;
#pragma unroll
        for (int j = 0; j < 4; ++j) { m[j] = acc[i][j] + bm[j]; v[j] = acc[i][j + 4] + bv[j]; }
        *(f4*)(out + OUT_MU  + base + tx * 4) = m;
        *(f4*)(out + OUT_VAR + base + tx * 4) = v;
    }
}

// ---------------------------------------------------------------------------
extern "C" void kernel_launch(void* const* d_in, const int* in_sizes, int n_in,
                              void* d_out, int out_size, void* d_ws, size_t ws_size,
                              hipStream_t stream) {
    const float* x       = (const float*)d_in[0];
    const float* time_x  = (const float*)d_in[1];
    const float* W_embed = (const float*)d_in[2];
    const float* b_embed = (const float*)d_in[3];
    const float* W_mu    = (const float*)d_in[4];
    const float* b_mu    = (const float*)d_in[5];
    const float* W_var   = (const float*)d_in[6];
    const float* b_var   = (const float*)d_in[7];
    float* out = (float*)d_out;

    const size_t need = (size_t)N_ * B_ * L_ * sizeof(float);
    const int nblk = N_ * (B_ / BT);   // 321*4 = 1284

    if (ws_size >= need) {
        float* xp = (float*)d_ws;
        k_transpose<<<dim3(11, 11, B_), dim3(32, 8), 0, stream>>>(x, xp);
        k_fused<true><<<nblk, 64, 0, stream>>>(xp, time_x, W_embed, b_embed,
                                               W_mu, b_mu, W_var, b_var, out);
    } else {
        k_fused<false><<<nblk, 64, 0, stream>>>(x, time_x, W_embed, b_embed,
                                                W_mu, b_mu, W_var, b_var, out);
    }
}

// Round 2
// 253.983 us; speedup vs baseline: 1.7913x; 1.7913x over previous
//
#include <hip/hip_runtime.h>
#include <math.h>

#define B_   128
#define L_   336
#define N_   321
#define E_   128
#define LAT_ 64

typedef float f4 __attribute__((ext_vector_type(4)));

// out layout (flat concat, fp32):
#define OUT_HH  (B_*N_*E_)
#define OUT_MU  (2*B_*N_*E_)
#define OUT_VAR (2*B_*N_*E_ + B_*N_*LAT_)

// ---------------------------------------------------------------------------
// Kernel 1: transpose x[B][L][N] -> xp2[N][L][B]  (b innermost so the GEMM's
// A-tile staging is contiguous). Tile: 32n x 32b x 4l per 256-thread block.
// ---------------------------------------------------------------------------
__global__ __launch_bounds__(256) void k_transpose(const float* __restrict__ x,
                                                   float* __restrict__ xp2) {
    __shared__ float t[4][32][33];   // [l][n][b], stride 33 -> conflict-free
    const int n0 = blockIdx.x * 32;
    const int b0 = blockIdx.y * 32;
    const int l0 = blockIdx.z * 4;
    const int tid = threadIdx.x;
    const int tn = tid & 31;
    const int tb = tid >> 5;         // 0..7
    const int nn = n0 + tn;

    if (nn < N_) {
#pragma unroll
        for (int l = 0; l < 4; ++l)
#pragma unroll
            for (int p = 0; p < 4; ++p) {
                const int b = b0 + tb + 8 * p;
                t[l][tn][tb + 8 * p] = x[(size_t)b * (L_ * N_) + (size_t)(l0 + l) * N_ + nn];
            }
    }
    __syncthreads();
#pragma unroll
    for (int p = 0; p < 4; ++p) {
        const int idx = tid + 256 * p;
        const int row = idx >> 3;        // 0..127 = l*32 + n2
        const int bq  = idx & 7;
        const int l   = row >> 5;
        const int n2  = row & 31;
        if (n0 + n2 < N_) {
            f4 v;
#pragma unroll
            for (int j = 0; j < 4; ++j) v[j] = t[l][n2][bq * 4 + j];
            *(f4*)(xp2 + (size_t)(n0 + n2) * (L_ * B_) + (size_t)(l0 + l) * B_ + b0 + bq * 4) = v;
        }
    }
}

// ---------------------------------------------------------------------------
// Kernel 2: fused grouped GEMM. 256 threads (4 waves) per block.
// Block tile: 64 rows(b) x 128 cols; grid = N*2 (XCD-swizzled).
// Per thread: acc[8][4] (rows trow*8.., cols tx*4..).
// LDS 40KB: A2t[128][64] (h_hat^T, chunk-XOR swizzle; start aliases stage-1
// A1[16][64]) + Wbuf[16][128] (W1 in stage 1, W2 in stage 2).
// ---------------------------------------------------------------------------
#define KT 16

template <bool XP>
__global__ __launch_bounds__(256, 3) void k_fused(const float* __restrict__ xsrc,
                                                  const float* __restrict__ time_x,
                                                  const float* __restrict__ W_embed,
                                                  const float* __restrict__ b_embed,
                                                  const float* __restrict__ W_mu,
                                                  const float* __restrict__ b_mu,
                                                  const float* __restrict__ W_var,
                                                  const float* __restrict__ b_var,
                                                  float* __restrict__ out) {
    __shared__ float A2t[128 * 64];      // 32KB; A1[16][64] aliases the start
    __shared__ float Wbuf[KT * 128];     // 8KB; W1 / W2
    float* A1 = A2t;

    const int tid  = threadIdx.x;
    const int tx   = tid & 31;           // col group (4 cols)
    const int trow = tid >> 5;           // 0..7 row group (8 rows)

    // bijective XCD swizzle (nwg = 642 = 8*80 + 2)
    int bid = blockIdx.x;
    {
        const int nwg = N_ * 2, q = nwg / 8, r = nwg % 8;
        const int xcd = bid % 8, lid = bid / 8;
        bid = (xcd < r ? xcd * (q + 1) : r * (q + 1) + (xcd - r) * q) + lid;
    }
    const int n  = bid >> 1;
    const int b0 = (bid & 1) * 64;

    float acc[8][4];
#pragma unroll
    for (int i = 0; i < 8; ++i)
#pragma unroll
        for (int j = 0; j < 4; ++j) acc[i][j] = 0.f;

    // ------------------------- stage 1: h, K = 336 -------------------------
    const int akk = tid >> 4, arq = tid & 15;      // A staging: [16][64]
    const int wk0 = tid >> 5, wc0 = tid & 31;      // W staging: [16][128], 2 rounds

    for (int k0 = 0; k0 < L_; k0 += KT) {
        f4 av;
        if (XP) {
            av = *(const f4*)(xsrc + (size_t)n * (L_ * B_) + (size_t)(k0 + akk) * B_ + b0 + arq * 4);
        } else {
#pragma unroll
            for (int j = 0; j < 4; ++j) {
                const int r = arq * 4 + j;
                av[j] = xsrc[(size_t)(b0 + r) * (L_ * N_) + (size_t)(k0 + akk) * N_ + n];
            }
        }
        f4 wv0 = *(const f4*)(W_embed + (size_t)n * (L_ * E_) + (size_t)(k0 + wk0) * E_ + wc0 * 4);
        f4 wv1 = *(const f4*)(W_embed + (size_t)n * (L_ * E_) + (size_t)(k0 + wk0 + 8) * E_ + wc0 * 4);

        __syncthreads();                           // prev tile's readers done
        *(f4*)(A1 + akk * 64 + arq * 4) = av;
        *(f4*)(Wbuf + wk0 * 128 + wc0 * 4) = wv0;
        *(f4*)(Wbuf + (wk0 + 8) * 128 + wc0 * 4) = wv1;
        __syncthreads();                           // tile visible

#pragma unroll
        for (int kk = 0; kk < KT; ++kk) {
            f4 a0 = *(const f4*)(A1 + kk * 64 + trow * 8);       // broadcast
            f4 a1 = *(const f4*)(A1 + kk * 64 + trow * 8 + 4);   // broadcast
            f4 w  = *(const f4*)(Wbuf + kk * 128 + tx * 4);
#pragma unroll
            for (int i = 0; i < 4; ++i)
#pragma unroll
                for (int j = 0; j < 4; ++j) {
                    acc[i][j]     += a0[i] * w[j];
                    acc[i + 4][j] += a1[i] * w[j];
                }
        }
    }
    __syncthreads();   // all stage-1 LDS reads done before A1 region reuse

    // --------- epilogue 1: bias, h, sigmoid(time_x)*h, h_hat^T -> LDS ------
    f4 bev = *(const f4*)(b_embed + n * E_ + tx * 4);
    f4 hh[8];
#pragma unroll
    for (int i = 0; i < 8; ++i) {
        const int row = b0 + trow * 8 + i;
        const size_t base = ((size_t)row * N_ + n) * E_ + tx * 4;
        f4 h;
#pragma unroll
        for (int j = 0; j < 4; ++j) h[j] = acc[i][j] + bev[j];
        *(f4*)(out + base) = h;
        f4 tv = *(const f4*)(time_x + base);
        f4 hv;
#pragma unroll
        for (int j = 0; j < 4; ++j) hv[j] = h[j] * (1.f / (1.f + expf(-tv[j])));
        *(f4*)(out + OUT_HH + base) = hv;
        hh[i] = hv;
    }
    // h_hat^T into A2t[e][r], 16B chunks XOR-swizzled: pc = (r>>2) ^ (e&15)
#pragma unroll
    for (int c = 0; c < 2; ++c) {
#pragma unroll
        for (int j = 0; j < 4; ++j) {
            const int e  = tx * 4 + j;
            const int pc = (2 * trow + c) ^ (e & 15);
            f4 v;
#pragma unroll
            for (int q = 0; q < 4; ++q) v[q] = hh[4 * c + q][j];
            *(f4*)(A2t + e * 64 + pc * 4) = v;
        }
    }

    // ------------------- stage 2: [mu|var], K = E = 128 ---------------------
#pragma unroll
    for (int i = 0; i < 8; ++i)
#pragma unroll
        for (int j = 0; j < 4; ++j) acc[i][j] = 0.f;

    for (int e0 = 0; e0 < E_; e0 += KT) {
        f4 wv[2];
#pragma unroll
        for (int t = 0; t < 2; ++t) {
            const int kk  = wk0 + 8 * t;
            const int col = wc0 * 4;
            const float* src = (col < 64)
                ? (W_mu  + (size_t)n * (E_ * LAT_) + (size_t)(e0 + kk) * LAT_ + col)
                : (W_var + (size_t)n * (E_ * LAT_) + (size_t)(e0 + kk) * LAT_ + (col - 64));
            wv[t] = *(const f4*)src;
        }
        __syncthreads();   // iter0: A2t writes + stage-1 Wbuf readers done; else prev compute done
        *(f4*)(Wbuf + wk0 * 128 + wc0 * 4) = wv[0];
        *(f4*)(Wbuf + (wk0 + 8) * 128 + wc0 * 4) = wv[1];
        __syncthreads();

#pragma unroll
        for (int kk = 0; kk < KT; ++kk) {
            const int e = e0 + kk;
            f4 a0 = *(const f4*)(A2t + e * 64 + ((2 * trow + 0) ^ (e & 15)) * 4);  // broadcast
            f4 a1 = *(const f4*)(A2t + e * 64 + ((2 * trow + 1) ^ (e & 15)) * 4);  // broadcast
            f4 w  = *(const f4*)(Wbuf + kk * 128 + tx * 4);
#pragma unroll
            for (int i = 0; i < 4; ++i)
#pragma unroll
                for (int j = 0; j < 4; ++j) {
                    acc[i][j]     += a0[i] * w[j];
                    acc[i + 4][j] += a1[i] * w[j];
                }
        }
    }

    // ------------------------- epilogue 2: mu / var -------------------------
    f4 bb;
    if (tx < 16) bb = *(const f4*)(b_mu  + n * LAT_ + tx * 4);
    else         bb = *(const f4*)(b_var + n * LAT_ + (tx - 16) * 4);
#pragma unroll
    for (int i = 0; i < 8; ++i) {
        const int row = b0 + trow * 8 + i;
        const size_t base = ((size_t)row * N_ + n) * LAT_;
        f4 o;
#pragma unroll
        for (int j = 0; j < 4; ++j) o[j] = acc[i][j] + bb[j];
        if (tx < 16) *(f4*)(out + OUT_MU  + base + tx * 4) = o;
        else         *(f4*)(out + OUT_VAR + base + (tx - 16) * 4) = o;
    }
}

// ---------------------------------------------------------------------------
extern "C" void kernel_launch(void* const* d_in, const int* in_sizes, int n_in,
                              void* d_out, int out_size, void* d_ws, size_t ws_size,
                              hipStream_t stream) {
    const float* x       = (const float*)d_in[0];
    const float* time_x  = (const float*)d_in[1];
    const float* W_embed = (const float*)d_in[2];
    const float* b_embed = (const float*)d_in[3];
    const float* W_mu    = (const float*)d_in[4];
    const float* b_mu    = (const float*)d_in[5];
    const float* W_var   = (const float*)d_in[6];
    const float* b_var   = (const float*)d_in[7];
    float* out = (float*)d_out;

    const size_t need = (size_t)N_ * L_ * B_ * sizeof(float);
    const int nblk = N_ * 2;   // 642

    if (ws_size >= need) {
        float* xp2 = (float*)d_ws;
        k_transpose<<<dim3(11, 4, 84), 256, 0, stream>>>(x, xp2);
        k_fused<true><<<nblk, 256, 0, stream>>>(xp2, time_x, W_embed, b_embed,
                                                W_mu, b_mu, W_var, b_var, out);
    } else {
        k_fused<false><<<nblk, 256, 0, stream>>>(x, time_x, W_embed, b_embed,
                                                 W_mu, b_mu, W_var, b_var, out);
    }
}